// Round 6
// baseline (60.206 us; speedup 1.0000x reference)
//
#include <hip/hip_runtime.h>
#include <hip/hip_bf16.h>

// AdLIF SNN forward, MI355X. B=512, T=500, NIN=96, H=512, NOUT=2.
//
// One block per batch row, 512 threads (8 waves), wave wv owns h in
// [wv*64, wv*64+64). Single-barrier-per-chunk software pipeline:
//   phase p: { issue ds_reads of I'(p-1) | MFMA(p) -> Ibuf[p&1] |
//              stage x(p+1) (write-late) + issue x(p+2) (load-early) |
//              spec-scan chunk p-1 from Ibuf[(p-1)&1] | barrier }
// I' double-buffered so scan(p-1) and MFMA(p) coexist in one phase.
//  - W1 fragments persistent in registers with oma=(1-alpha) folded in
//    => MFMA produces I' = oma*I directly; spec scan = v=fma(al,v,I').
//  - Speculation: no spike => a==0, spk==0. m=max(v) per chunk; m>1 sets
//    flag[j&3] (set phase j+1, read phase j+2, cleared phase j+3 -- 4-slot
//    ring avoids set/clear races). On flag: restore 2-deep v checkpoint
//    (a,spk provably 0 at first flagged chunk), exact re-run of chunks
//    j, j+1 from the two live I-buffers, then exact tail loop (restages x,
//    recomputes I', full Wrec recurrence). Never taken on this data; exact
//    if taken.

#define B_ 512
#define T_ 500
#define NIN_ 96
#define H_ 512
#define CH 16
#define NCH 32           // 31 full chunks + 1 partial (4 steps)
#define LASTN (T_ - (NCH - 1) * CH)   // 4
#define XPAD 104         // shorts per x row (208 B pitch)
#define PT 24            // shorts per I row (48 B pitch)

typedef __attribute__((ext_vector_type(8))) short bf16x8;  // 8 bf16 = 4 VGPR
typedef __attribute__((ext_vector_type(4))) float f32x4;

__device__ __forceinline__ unsigned short f2bf(float f) {
    union { __hip_bfloat16 h; unsigned short s; } u;
    u.h = __float2bfloat16(f);
    return u.s;
}
__device__ __forceinline__ unsigned pk2(float lo, float hi) {
    return (unsigned)f2bf(lo) | ((unsigned)f2bf(hi) << 16);
}
__device__ __forceinline__ float bf_lo(unsigned dw) {
    return __uint_as_float(dw << 16);
}
__device__ __forceinline__ float bf_hi(unsigned dw) {
    return __uint_as_float(dw & 0xffff0000u);
}

// Exact AdLIF cold path. Irow holds I' = oma*I (bf16, oma-folded).
// vnew = (al*v)*(1-spk) + I' + oma*(racc - a).
__device__ __noinline__ void exact_steps(
    int nsteps, const unsigned short* Irow, float* spk_lds,
    const float* __restrict__ Wrec, int tid,
    float al, float oma, float rh, float be,
    float& v, float& a, float& spk)
{
    for (int tt = 0; tt < nsteps; ++tt) {
        float Ip = __uint_as_float(((unsigned)Irow[tt]) << 16);
        float racc = 0.f;
        for (int hp = 0; hp < H_; ++hp) {
            if (spk_lds[hp] != 0.f) racc += Wrec[(size_t)tid * H_ + hp];
        }
        float vnew = (al * v) * (1.f - spk) + Ip + oma * (racc - a);
        spk = (vnew - 1.f) > 0.f ? 1.f : 0.f;
        a = fmaf(be, spk, rh * a);
        v = vnew;
        __syncthreads();
        spk_lds[tid] = spk;
        __syncthreads();
    }
}

__global__ __launch_bounds__(512, 4) void snn_pipe(
    const float* __restrict__ x,      // [B, T, NIN]
    const float* __restrict__ W1,     // [H, NIN]
    const float* __restrict__ Wrec,   // [H, H]
    const float* __restrict__ W2,     // [2, H]
    const float* __restrict__ alpha,  // [H]
    const float* __restrict__ rho,    // [H]
    const float* __restrict__ beta_a, // [H]
    float* __restrict__ out)          // [B, 2]
{
    const int b    = blockIdx.x;
    const int tid  = threadIdx.x;
    const int wv   = tid >> 6;
    const int lane = tid & 63;
    const int lq   = lane >> 4;      // k-/t-quad (0..3)
    const int lr   = lane & 15;

    __shared__ __align__(16) unsigned short Ilds[2][H_ * PT];   // I' dbuf, 48 KB
    __shared__ __align__(16) unsigned short xlds[2][CH * XPAD]; // x dbuf, 6.5 KB
    __shared__ float spk_lds[H_];
    __shared__ int   flagLds[4];     // ring: chunk j -> slot j&3
    __shared__ float red[16];

    // --- W1 fragments (persistent), oma[h] folded in.
    // Tile i covers h = wv*64 + i*16 + lr; lane holds k = kb*32 + lq*8 + j.
    bf16x8 wfrag[4][3];
    #pragma unroll
    for (int i = 0; i < 4; ++i) {
        const int h = wv * 64 + i * 16 + lr;
        const float omaf = 1.0f - alpha[h];
        const float* wrow = W1 + h * NIN_;
        #pragma unroll
        for (int kb = 0; kb < 3; ++kb) {
            const float* p = wrow + kb * 32 + lq * 8;
            float4 u0 = *reinterpret_cast<const float4*>(p);
            float4 u1 = *reinterpret_cast<const float4*>(p + 4);
            union { unsigned d[4]; bf16x8 v8; } pk;
            pk.d[0] = pk2(omaf * u0.x, omaf * u0.y);
            pk.d[1] = pk2(omaf * u0.z, omaf * u0.w);
            pk.d[2] = pk2(omaf * u1.x, omaf * u1.y);
            pk.d[3] = pk2(omaf * u1.z, omaf * u1.w);
            wfrag[i][kb] = pk.v8;
        }
    }

    const float al  = alpha[tid];
    const float oma = 1.0f - al;
    const float rh  = rho[tid];
    const float be  = beta_a[tid];

    // --- x staging: 192 threads, 32 B each per chunk (coalesced rows).
    const float4* xb4 = reinterpret_cast<const float4*>(x + (size_t)b * T_ * NIN_);
    const int stg = (tid < 192);
    const int st  = tid / 12;        // row t within chunk (0..15)
    const int sq  = tid % 12;        // 16B segment (12 per 96-float row? 24 f4)
    float4 xa = make_float4(0.f,0.f,0.f,0.f), xbv = make_float4(0.f,0.f,0.f,0.f);

    auto XLOAD = [&](int c) {                 // issue global loads (early)
        if (stg) {
            int t = c * CH + st;
            if (t < T_) {
                xa  = xb4[t * 24 + sq * 2];
                xbv = xb4[t * 24 + sq * 2 + 1];
            } else {
                xa  = make_float4(0.f,0.f,0.f,0.f);
                xbv = make_float4(0.f,0.f,0.f,0.f);
            }
        }
    };
    auto XWRITE = [&](int c) {                // convert + LDS write (late)
        if (stg) {
            uint4 w;
            w.x = pk2(xa.x, xa.y);   w.y = pk2(xa.z, xa.w);
            w.z = pk2(xbv.x, xbv.y); w.w = pk2(xbv.z, xbv.w);
            *reinterpret_cast<uint4*>(&xlds[c & 1][st * XPAD + sq * 8]) = w;
        }
    };
    auto DO_MFMA = [&](int cc) {   // I'(cc) -> Ilds[cc&1]
        f32x4 acc[4] = {{0.f,0.f,0.f,0.f},{0.f,0.f,0.f,0.f},
                        {0.f,0.f,0.f,0.f},{0.f,0.f,0.f,0.f}};
        #pragma unroll
        for (int kb = 0; kb < 3; ++kb) {
            bf16x8 xf = *reinterpret_cast<const bf16x8*>(
                &xlds[cc & 1][lr * XPAD + kb * 32 + lq * 8]);
            #pragma unroll
            for (int i = 0; i < 4; ++i)
                acc[i] = __builtin_amdgcn_mfma_f32_16x16x32_bf16(
                    xf, wfrag[i][kb], acc[i], 0, 0, 0);
        }
        unsigned short* Ib = Ilds[cc & 1];
        #pragma unroll
        for (int i = 0; i < 4; ++i) {
            const int h = wv * 64 + i * 16 + lr;
            uint2 w;
            w.x = pk2(acc[i][0], acc[i][1]);
            w.y = pk2(acc[i][2], acc[i][3]);
            *reinterpret_cast<uint2*>(&Ib[h * PT + lq * 4]) = w;
        }
    };

    XLOAD(0); XWRITE(0);     // chunk 0 synchronously
    XLOAD(1);                // chunk 1 in flight (written during phase 0)
    if (tid < 4) flagLds[tid] = 0;

    float v = 0.f, a = 0.f, spk = 0.f;
    float vckA = 0.f, vckB = 0.f;    // v at start of chunk (even/odd slots)

    __syncthreads();         // xlds[0] + flags visible

    #pragma unroll 1
    for (int p = 0; p <= NCH; ++p) {
        // --- speculation check for chunk f = p-2 (flag set in phase p-1).
        if (p >= 2 && flagLds[(p - 2) & 3]) {      // block-uniform
            const int f = p - 2;
            v = (f & 1) ? vckB : vckA;             // a,spk provably 0
            a = 0.f; spk = 0.f;
            spk_lds[tid] = 0.f;
            __syncthreads();
            // chunks f, f+1 from the two live I-buffers (f <= NCH-2).
            exact_steps(CH, &Ilds[f & 1][tid * PT], spk_lds, Wrec,
                        tid, al, oma, rh, be, v, a, spk);
            exact_steps((f + 1 == NCH - 1) ? LASTN : CH,
                        &Ilds[(f + 1) & 1][tid * PT], spk_lds, Wrec,
                        tid, al, oma, rh, be, v, a, spk);
            // exact tail: restage + recompute I' per chunk.
            for (int jj = f + 2; jj < NCH; ++jj) {
                __syncthreads();
                XLOAD(jj); XWRITE(jj);
                __syncthreads();
                DO_MFMA(jj);
                __syncthreads();
                exact_steps((jj == NCH - 1) ? LASTN : CH,
                            &Ilds[jj & 1][tid * PT], spk_lds, Wrec,
                            tid, al, oma, rh, be, v, a, spk);
            }
            goto readout;
        }
        if (p >= 3 && tid == 0) flagLds[(p - 3) & 3] = 0;  // recycle slot

        // --- issue scan reads early (chunk j = p-1), latency under MFMA.
        uint4 ra = {0,0,0,0}, rb = {0,0,0,0};
        const int j = p - 1;
        if (p >= 1) {
            const unsigned short* Irow = &Ilds[j & 1][tid * PT];
            ra = *reinterpret_cast<const uint4*>(Irow);
            rb = *reinterpret_cast<const uint4*>(Irow + 8);
        }

        if (p < NCH) DO_MFMA(p);            // -> Ilds[p&1]
        if (p + 1 < NCH) XWRITE(p + 1);     // loads from phase p-1 landed
        if (p + 2 < NCH) XLOAD(p + 2);      // in flight until next phase

        if (p >= 1) {
            if (j & 1) vckB = v; else vckA = v;   // checkpoint chunk-j start
            float m = 0.f;
            #define U2(dw) { \
                v = fmaf(al, v, bf_lo(dw)); m = fmaxf(m, v); \
                v = fmaf(al, v, bf_hi(dw)); m = fmaxf(m, v); }
            if (j == NCH - 1) {             // partial: 4 steps
                U2(ra.x) U2(ra.y)
            } else {
                U2(ra.x) U2(ra.y) U2(ra.z) U2(ra.w)
                U2(rb.x) U2(rb.y) U2(rb.z) U2(rb.w)
            }
            #undef U2
            if (m > 1.f) flagLds[j & 3] = 1;     // benign race, all store 1
        }
        __syncthreads();
    }

    // --- last chunk's speculation (flag set in phase NCH).
    if (flagLds[(NCH - 1) & 3]) {
        v = vckB;                            // NCH-1 = 31 (odd slot)
        a = 0.f; spk = 0.f;
        spk_lds[tid] = 0.f;
        __syncthreads();
        exact_steps(LASTN, &Ilds[(NCH - 1) & 1][tid * PT], spk_lds, Wrec,
                    tid, al, oma, rh, be, v, a, spk);
    }

readout:
    {
        // out[b,n] = sum_h v_h * W2[n,h]
        float p0 = v * W2[tid];
        float p1 = v * W2[H_ + tid];
        #pragma unroll
        for (int off = 32; off > 0; off >>= 1) {
            p0 += __shfl_down(p0, off, 64);
            p1 += __shfl_down(p1, off, 64);
        }
        if (lane == 0) { red[wv * 2] = p0; red[wv * 2 + 1] = p1; }
        __syncthreads();
        if (tid == 0) {
            float s0 = 0.f, s1 = 0.f;
            #pragma unroll
            for (int w8 = 0; w8 < 8; ++w8) {
                s0 += red[w8 * 2]; s1 += red[w8 * 2 + 1];
            }
            out[b * 2 + 0] = s0;
            out[b * 2 + 1] = s1;
        }
    }
}

extern "C" void kernel_launch(void* const* d_in, const int* in_sizes, int n_in,
                              void* d_out, int out_size, void* d_ws, size_t ws_size,
                              hipStream_t stream) {
    const float* x      = (const float*)d_in[0];
    const float* W1     = (const float*)d_in[1];
    const float* Wrec   = (const float*)d_in[2];
    const float* W2     = (const float*)d_in[3];
    const float* alpha  = (const float*)d_in[4];
    const float* rho    = (const float*)d_in[5];
    const float* beta_a = (const float*)d_in[6];
    float* out = (float*)d_out;

    snn_pipe<<<dim3(B_), dim3(H_), 0, stream>>>(x, W1, Wrec, W2, alpha, rho, beta_a, out);
}